// Round 1
// baseline (591.392 us; speedup 1.0000x reference)
//
#include <hip/hip_runtime.h>
#include <math.h>

#define B   32
#define T   50
#define N1  50001
#define D   128
#define KP  16
#define MP  50
#define HID 72
#define BT  (B*T)

// ---------------- helpers ----------------
__device__ __forceinline__ float blockReduceSum128(float val, volatile float* sbuf) {
    // blockDim.x == 128 (2 waves of 64)
    for (int off = 32; off > 0; off >>= 1) val += __shfl_down(val, off, 64);
    __syncthreads();                       // protect sbuf from previous use
    if ((threadIdx.x & 63) == 0) sbuf[threadIdx.x >> 6] = val;
    __syncthreads();
    return sbuf[0] + sbuf[1];
}

// ---------------- 1. ProxySelection MLP per (b,t) ----------------
__global__ void k_proxy_x2(const int* __restrict__ session,
                           const float* __restrict__ I_emb,
                           const float* __restrict__ EP_emb,
                           const float* __restrict__ WP1,
                           const float* __restrict__ WP2,
                           float* __restrict__ X2) {
    int bt = blockIdx.x; int t = bt % T;
    int tid = threadIdx.x;                 // 128
    __shared__ float x[D];
    __shared__ float h[HID];
    int sid = session[bt];
    float val = 0.f;
    if (sid != 0) val = I_emb[(size_t)sid * D + tid] + EP_emb[(t + MP - T) * D + tid];
    x[tid] = val;
    __syncthreads();
    if (tid < HID) {
        float acc = 0.f;
        const float* w = WP1 + tid * D;
        for (int k = 0; k < D; ++k) acc += x[k] * w[k];
        h[tid] = acc > 0.f ? acc : 0.1f * acc;   // leaky_relu 0.1
    }
    __syncthreads();
    if (tid < KP) {
        float acc = 0.f;
        const float* w = WP2 + tid * HID;
        for (int k = 0; k < HID; ++k) acc += h[k] * w[k];
        X2[bt * KP + tid] = acc;
    }
}

// ---------------- 2. softmax head: pi, p_s, v, orthogonal ----------------
__global__ void k_proxy_head(const float* __restrict__ X2,
                             const int* __restrict__ lengths,
                             const int* __restrict__ tau_i,
                             const float* __restrict__ P_emb,
                             const float* __restrict__ V,
                             float* __restrict__ ps_o,
                             float* __restrict__ v_o,
                             float* __restrict__ orth_o) {
    int b = blockIdx.x; int tid = threadIdx.x;   // 128
    __shared__ float pi[KP];
    __shared__ float vn[KP];
    __shared__ float sbuf[2];
    float tau = (float)tau_i[0];
    float lf = (float)lengths[b];
    if (tid < KP) {
        float s = 0.f;
        for (int t = 0; t < T; ++t) s += X2[(b * T + t) * KP + tid];
        pi[tid] = (s / lf) / tau;
    }
    if (tid < KP) {   // V row norms
        float s = 0.f;
        for (int d = 0; d < D; ++d) { float z = V[tid * D + d]; s += z * z; }
        vn[tid] = fmaxf(sqrtf(s), 1e-12f);
    }
    __syncthreads();
    if (tid == 0) {
        float m = pi[0];
        for (int k = 1; k < KP; ++k) m = fmaxf(m, pi[k]);
        float s = 0.f;
        for (int k = 0; k < KP; ++k) { float e = expf(pi[k] - m); pi[k] = e; s += e; }
        for (int k = 0; k < KP; ++k) pi[k] /= s;
    }
    __syncthreads();
    float p = 0.f, vt = 0.f;
    for (int k = 0; k < KP; ++k) {
        p  += pi[k] * P_emb[k * D + tid];
        vt += pi[k] * (V[k * D + tid] / vn[k]);
    }
    float vsq = blockReduceSum128(vt * vt, sbuf);
    float vv = vt / fmaxf(sqrtf(vsq), 1e-12f);
    float psq = blockReduceSum128(p * p, sbuf);
    float dvp = blockReduceSum128(vv * p, sbuf);
    ps_o[b * D + tid] = p;
    v_o[b * D + tid] = vv;
    if (tid == 0) orth_o[b] = fabsf(dvp) / sqrtf(psq);
}

// ---------------- 3. Xs, q, k, v ----------------
__global__ void k_xs_qkv(const int* __restrict__ session,
                         const int* __restrict__ lengths,
                         const float* __restrict__ I_emb,
                         const float* __restrict__ ES_emb,
                         const float* __restrict__ Wq,
                         const float* __restrict__ Wk,
                         const float* __restrict__ Wv,
                         float* __restrict__ xs_o, float* __restrict__ q_o,
                         float* __restrict__ k_o, float* __restrict__ v_o) {
    int bt = blockIdx.x; int b = bt / T; int t = bt % T;
    int tid = threadIdx.x;  // 128
    __shared__ float xs[D];
    int sid = session[bt];
    int es = t + 1 - (T - lengths[b]); if (es < 0) es = 0;
    float x = I_emb[(size_t)sid * D + tid] + ES_emb[es * D + tid];
    xs[tid] = x;
    __syncthreads();
    float aq = 0.f, ak = 0.f, av = 0.f;
    const float* wq = Wq + tid * D;
    const float* wk = Wk + tid * D;
    const float* wv = Wv + tid * D;
    for (int k = 0; k < D; ++k) { float xv = xs[k]; aq += xv * wq[k]; ak += xv * wk[k]; av += xv * wv[k]; }
    xs_o[bt * D + tid] = x; q_o[bt * D + tid] = aq; k_o[bt * D + tid] = ak; v_o[bt * D + tid] = av;
}

// ---------------- 4. attention: scores + softmax + attn@vv ----------------
__global__ void k_attn(const int* __restrict__ session,
                       const float* __restrict__ q,
                       const float* __restrict__ kk,
                       const float* __restrict__ vv,
                       float* __restrict__ ho) {
    int bt = blockIdx.x; int b = bt / T; int t = bt % T;
    int tid = threadIdx.x;  // 128
    __shared__ float qs[D];
    __shared__ float attn[T];
    qs[tid] = q[bt * D + tid];
    __syncthreads();
    if (tid < T) {
        int s = tid;
        bool allowed = (s == 0) || ((s <= t) && (session[b * T + s] != 0));
        float sc = -1e9f;
        if (allowed) {
            float a = 0.f;
            const float* kr = kk + (size_t)(b * T + s) * D;
            for (int d = 0; d < D; ++d) a += qs[d] * kr[d];
            sc = a * 0.088388347648318447f;  // 1/sqrt(128)
        }
        attn[s] = sc;
    }
    __syncthreads();
    if (tid == 0) {
        float m = attn[0];
        for (int s = 1; s < T; ++s) m = fmaxf(m, attn[s]);
        float sum = 0.f;
        for (int s = 0; s < T; ++s) { float e = expf(attn[s] - m); attn[s] = e; sum += e; }
        float inv = 1.f / sum;
        for (int s = 0; s < T; ++s) attn[s] *= inv;
    }
    __syncthreads();
    float acc = 0.f;
    for (int s = 0; s < T; ++s) acc += attn[s] * vv[(size_t)(b * T + s) * D + tid];
    ho[bt * D + tid] = acc;
}

// ---------------- 5. Wo + residual + LN1 ----------------
__global__ void k_post_attn(const int* __restrict__ session,
                            const float* __restrict__ ho,
                            const float* __restrict__ Wo,
                            const float* __restrict__ xs,
                            const float* __restrict__ g1, const float* __restrict__ b1,
                            float* __restrict__ h_o) {
    int bt = blockIdx.x; int tid = threadIdx.x;
    __shared__ float hr[D];
    __shared__ float sbuf[2];
    hr[tid] = ho[bt * D + tid];
    __syncthreads();
    float a = 0.f;
    const float* w = Wo + tid * D;
    for (int k = 0; k < D; ++k) a += hr[k] * w[k];
    float x = a + xs[bt * D + tid];
    float mean = blockReduceSum128(x, sbuf) * (1.f / D);
    float dx = x - mean;
    float var = blockReduceSum128(dx * dx, sbuf) * (1.f / D);
    float y = dx * rsqrtf(var + 1e-6f) * g1[tid] + b1[tid];
    h_o[bt * D + tid] = y * ((session[bt] != 0) ? 1.f : 0.f);
}

// ---------------- 6. FFN + LN2 + projection -> G, Fn2 ----------------
__global__ void k_ffn_G(const int* __restrict__ session,
                        const float* __restrict__ h,
                        const float* __restrict__ FF1, const float* __restrict__ FF2,
                        const float* __restrict__ g2, const float* __restrict__ b2,
                        const float* __restrict__ ps, const float* __restrict__ v,
                        float* __restrict__ G, float* __restrict__ Fn2) {
    int bt = blockIdx.x; int b = bt / T; int tid = threadIdx.x;
    __shared__ float hr[D];
    __shared__ float t1[D];
    __shared__ float sbuf[2];
    float hx = h[bt * D + tid];
    hr[tid] = hx;
    __syncthreads();
    float a = 0.f;
    const float* w1 = FF1 + tid * D;
    for (int k = 0; k < D; ++k) a += hr[k] * w1[k];
    t1[tid] = fmaxf(a, 0.f);
    __syncthreads();
    float f = 0.f;
    const float* w2 = FF2 + tid * D;
    for (int k = 0; k < D; ++k) f += t1[k] * w2[k];
    float x = f + hx;
    float mean = blockReduceSum128(x, sbuf) * (1.f / D);
    float dx = x - mean;
    float var = blockReduceSum128(dx * dx, sbuf) * (1.f / D);
    float ss = dx * rsqrtf(var + 1e-6f) * g2[tid] + b2[tid];
    ss *= (session[bt] != 0) ? 1.f : 0.f;
    float vb = v[b * D + tid];
    float vs = blockReduceSum128(vb * ss, sbuf);
    float ssp = ss - vb * vs;                  // s_s_proj
    float Fd = ps[b * D + tid] + ssp;          // F
    float Fv = blockReduceSum128(Fd * vb, sbuf);
    float Gd = Fd - Fv * vb;                   // G = F - (F.v) v
    float fn2 = blockReduceSum128(Fd * Fd, sbuf);
    G[bt * D + tid] = Gd;
    if (tid == 0) Fn2[bt] = fn2;
}

// ---------------- 7. per-item stats: In2pb[b,n] = ||I_n||^2 - (v_b . I_n)^2 ----------------
__global__ void k_item(const float* __restrict__ I_emb,
                       const float* __restrict__ v,
                       float* __restrict__ In2pb) {
    __shared__ float Is[64][129];
    __shared__ float vs[B][D];
    __shared__ float in2[64];
    int n0 = blockIdx.x * 64;
    int tid = threadIdx.x;  // 256
    for (int i = tid; i < B * D; i += 256) vs[i / D][i % D] = v[i];
    for (int i = tid; i < 64 * D; i += 256) {
        int r = i / D, c = i % D;
        int n = n0 + r;
        Is[r][c] = (n < N1) ? I_emb[(size_t)n * D + c] : 0.f;
    }
    __syncthreads();
    if (tid < 64) {
        float s = 0.f;
        for (int d = 0; d < D; ++d) { float z = Is[tid][d]; s += z * z; }
        in2[tid] = s;
    }
    __syncthreads();
    int nl = tid & 63;
    int b0 = (tid >> 6) * 8;
    int n = n0 + nl;
    if (n < N1) {
        for (int b = b0; b < b0 + 8; ++b) {
            float dot = 0.f;
            for (int d = 0; d < D; ++d) dot += Is[nl][d] * vs[b][d];
            In2pb[(size_t)b * N1 + n] = in2[nl] - dot * dot;
        }
    }
}

// ---------------- 8. big dist kernel: 64x64 tile, fp32 ----------------
#define TM 64
#define TN 64
#define KC 32
__global__ __launch_bounds__(256) void k_dist(const float* __restrict__ G,
                                              const float* __restrict__ I_emb,
                                              const float* __restrict__ Fn2,
                                              const float* __restrict__ In2pb,
                                              float* __restrict__ out) {
    __shared__ __align__(16) float Gs_t[KC][TM + 4];   // k-major, padded row=68 floats (16B-mult)
    __shared__ __align__(16) float Is_t[KC][TN + 4];
    int bt0 = blockIdx.y * TM;
    int n0  = blockIdx.x * TN;
    int tid = threadIdx.x;
    int tx = tid & 15, ty = tid >> 4;       // 16x16 threads, 4x4 micro-tile
    int r0 = tid >> 3;                      // 0..31
    int c4 = (tid & 7) * 4;                 // k-quad within chunk
    float acc[4][4];
    #pragma unroll
    for (int i = 0; i < 4; ++i)
        #pragma unroll
        for (int j = 0; j < 4; ++j) acc[i][j] = 0.f;

    for (int kc = 0; kc < D; kc += KC) {
        #pragma unroll
        for (int rr = r0; rr < TM; rr += 32) {
            float4 g = *(const float4*)&G[(size_t)(bt0 + rr) * D + kc + c4];
            Gs_t[c4 + 0][rr] = g.x; Gs_t[c4 + 1][rr] = g.y;
            Gs_t[c4 + 2][rr] = g.z; Gs_t[c4 + 3][rr] = g.w;
            int n = n0 + rr;
            float4 iv;
            if (n < N1) iv = *(const float4*)&I_emb[(size_t)n * D + kc + c4];
            else        iv = make_float4(0.f, 0.f, 0.f, 0.f);
            Is_t[c4 + 0][rr] = iv.x; Is_t[c4 + 1][rr] = iv.y;
            Is_t[c4 + 2][rr] = iv.z; Is_t[c4 + 3][rr] = iv.w;
        }
        __syncthreads();
        #pragma unroll
        for (int k = 0; k < KC; ++k) {
            float4 a4 = *(const float4*)&Gs_t[k][ty * 4];
            float4 b4 = *(const float4*)&Is_t[k][tx * 4];
            float av[4] = {a4.x, a4.y, a4.z, a4.w};
            float bv[4] = {b4.x, b4.y, b4.z, b4.w};
            #pragma unroll
            for (int i = 0; i < 4; ++i)
                #pragma unroll
                for (int j = 0; j < 4; ++j) acc[i][j] += av[i] * bv[j];
        }
        __syncthreads();
    }
    #pragma unroll
    for (int i = 0; i < 4; ++i) {
        int row = bt0 + ty * 4 + i;
        int b = row / T;
        float fn2 = Fn2[row];
        const float* inrow = In2pb + (size_t)b * N1;
        float* orow = out + (size_t)row * N1;
        #pragma unroll
        for (int j = 0; j < 4; ++j) {
            int col = n0 + tx * 4 + j;
            if (col < N1) orow[col] = fn2 + inrow[col] - 2.f * acc[i][j];
        }
    }
}

// ---------------- launch ----------------
extern "C" void kernel_launch(void* const* d_in, const int* in_sizes, int n_in,
                              void* d_out, int out_size, void* d_ws, size_t ws_size,
                              hipStream_t stream) {
    const int*   session = (const int*)d_in[0];
    const int*   lengths = (const int*)d_in[1];
    const int*   tau     = (const int*)d_in[2];
    const float* I_emb   = (const float*)d_in[5];
    const float* P_emb   = (const float*)d_in[6];
    const float* EP      = (const float*)d_in[7];
    const float* ES      = (const float*)d_in[8];
    const float* V       = (const float*)d_in[9];
    const float* WP1     = (const float*)d_in[10];
    const float* WP2     = (const float*)d_in[11];
    const float* Wq      = (const float*)d_in[12];
    const float* Wk      = (const float*)d_in[13];
    const float* Wv      = (const float*)d_in[14];
    const float* Wo      = (const float*)d_in[15];
    const float* FF1     = (const float*)d_in[16];
    const float* FF2     = (const float*)d_in[17];
    const float* g1      = (const float*)d_in[18];
    const float* b1      = (const float*)d_in[19];
    const float* g2      = (const float*)d_in[20];
    const float* b2      = (const float*)d_in[21];
    float* out = (float*)d_out;
    float* ws  = (float*)d_ws;

    // workspace layout (floats)
    float* wsX2   = ws;                       // 25600
    float* wsPs   = wsX2 + 25600;             // 4096
    float* wsV    = wsPs + 4096;              // 4096
    float* wsXs   = wsV + 4096;               // 204800
    float* wsQ    = wsXs + 204800;
    float* wsK    = wsQ + 204800;
    float* wsVv   = wsK + 204800;
    float* wsHo   = wsVv + 204800;
    float* wsH    = wsHo + 204800;
    float* wsG    = wsH + 204800;
    float* wsFn2  = wsG + 204800;             // 1600
    float* wsIn2  = wsFn2 + 1600;             // 32*50001

    float* orth_out = out + (size_t)BT * N1;

    k_proxy_x2 <<<BT, 128, 0, stream>>>(session, I_emb, EP, WP1, WP2, wsX2);
    k_proxy_head<<<B, 128, 0, stream>>>(wsX2, lengths, tau, P_emb, V, wsPs, wsV, orth_out);
    k_xs_qkv  <<<BT, 128, 0, stream>>>(session, lengths, I_emb, ES, Wq, Wk, Wv,
                                       wsXs, wsQ, wsK, wsVv);
    k_attn    <<<BT, 128, 0, stream>>>(session, wsQ, wsK, wsVv, wsHo);
    k_post_attn<<<BT, 128, 0, stream>>>(session, wsHo, Wo, wsXs, g1, b1, wsH);
    k_ffn_G   <<<BT, 128, 0, stream>>>(session, wsH, FF1, FF2, g2, b2, wsPs, wsV,
                                       wsG, wsFn2);
    k_item    <<<(N1 + 63) / 64, 256, 0, stream>>>(I_emb, wsV, wsIn2);
    dim3 gdist((N1 + TN - 1) / TN, BT / TM);
    k_dist    <<<gdist, 256, 0, stream>>>(wsG, I_emb, wsFn2, wsIn2, out);
}

// Round 3
// 455.595 us; speedup vs baseline: 1.2981x; 1.2981x over previous
//
#include <hip/hip_runtime.h>
#include <math.h>

#define B   32
#define T   50
#define N1  50001
#define D   128
#define KP  16
#define MP  50
#define HID 72
#define BT  (B*T)

typedef __attribute__((ext_vector_type(8))) short short8v;
typedef __attribute__((ext_vector_type(4))) float f32x4;

__device__ __forceinline__ unsigned short f2bf(float x) {
    unsigned u = __float_as_uint(x);
    u += 0x7fffu + ((u >> 16) & 1u);
    return (unsigned short)(u >> 16);
}

// ---------------- helpers ----------------
__device__ __forceinline__ float blockReduceSum128(float val, volatile float* sbuf) {
    // blockDim.x == 128 (2 waves of 64)
    for (int off = 32; off > 0; off >>= 1) val += __shfl_down(val, off, 64);
    __syncthreads();                       // protect sbuf from previous use
    if ((threadIdx.x & 63) == 0) sbuf[threadIdx.x >> 6] = val;
    __syncthreads();
    return sbuf[0] + sbuf[1];
}

// ---------------- 1. ProxySelection MLP per (b,t) ----------------
__global__ void k_proxy_x2(const int* __restrict__ session,
                           const float* __restrict__ I_emb,
                           const float* __restrict__ EP_emb,
                           const float* __restrict__ WP1,
                           const float* __restrict__ WP2,
                           float* __restrict__ X2) {
    int bt = blockIdx.x; int t = bt % T;
    int tid = threadIdx.x;                 // 128
    __shared__ __align__(16) float x[D];
    __shared__ float h[HID];
    int sid = session[bt];
    float val = 0.f;
    if (sid != 0) val = I_emb[(size_t)sid * D + tid] + EP_emb[(t + MP - T) * D + tid];
    x[tid] = val;
    __syncthreads();
    if (tid < HID) {
        float acc = 0.f;
        const float4* w4 = (const float4*)(WP1 + tid * D);
        const float4* x4 = (const float4*)x;
        #pragma unroll 8
        for (int k = 0; k < D / 4; ++k) {
            float4 w = w4[k]; float4 xv = x4[k];
            acc += xv.x * w.x + xv.y * w.y + xv.z * w.z + xv.w * w.w;
        }
        h[tid] = acc > 0.f ? acc : 0.1f * acc;   // leaky_relu 0.1
    }
    __syncthreads();
    if (tid < KP) {
        float acc = 0.f;
        const float* w = WP2 + tid * HID;
        for (int k = 0; k < HID; ++k) acc += h[k] * w[k];
        X2[bt * KP + tid] = acc;
    }
}

// ---------------- 2. softmax head: pi, p_s, v, orthogonal ----------------
__global__ void k_proxy_head(const float* __restrict__ X2,
                             const int* __restrict__ lengths,
                             const int* __restrict__ tau_i,
                             const float* __restrict__ P_emb,
                             const float* __restrict__ V,
                             float* __restrict__ ps_o,
                             float* __restrict__ v_o,
                             float* __restrict__ orth_o) {
    int b = blockIdx.x; int tid = threadIdx.x;   // 128
    __shared__ float pi[KP];
    __shared__ float vn[KP];
    __shared__ float sbuf[2];
    float tau = (float)tau_i[0];
    float lf = (float)lengths[b];
    if (tid < KP) {
        float s = 0.f;
        for (int t = 0; t < T; ++t) s += X2[(b * T + t) * KP + tid];
        pi[tid] = (s / lf) / tau;
    }
    if (tid < KP) {   // V row norms
        float s = 0.f;
        for (int d = 0; d < D; ++d) { float z = V[tid * D + d]; s += z * z; }
        vn[tid] = fmaxf(sqrtf(s), 1e-12f);
    }
    __syncthreads();
    if (tid == 0) {
        float m = pi[0];
        for (int k = 1; k < KP; ++k) m = fmaxf(m, pi[k]);
        float s = 0.f;
        for (int k = 0; k < KP; ++k) { float e = expf(pi[k] - m); pi[k] = e; s += e; }
        for (int k = 0; k < KP; ++k) pi[k] /= s;
    }
    __syncthreads();
    float p = 0.f, vt = 0.f;
    for (int k = 0; k < KP; ++k) {
        p  += pi[k] * P_emb[k * D + tid];
        vt += pi[k] * (V[k * D + tid] / vn[k]);
    }
    float vsq = blockReduceSum128(vt * vt, sbuf);
    float vv = vt / fmaxf(sqrtf(vsq), 1e-12f);
    float psq = blockReduceSum128(p * p, sbuf);
    float dvp = blockReduceSum128(vv * p, sbuf);
    ps_o[b * D + tid] = p;
    v_o[b * D + tid] = vv;
    if (tid == 0) orth_o[b] = fabsf(dvp) / sqrtf(psq);
}

// ---------------- 3. Xs, q, k, v ----------------
__global__ void k_xs_qkv(const int* __restrict__ session,
                         const int* __restrict__ lengths,
                         const float* __restrict__ I_emb,
                         const float* __restrict__ ES_emb,
                         const float* __restrict__ Wq,
                         const float* __restrict__ Wk,
                         const float* __restrict__ Wv,
                         float* __restrict__ xs_o, float* __restrict__ q_o,
                         float* __restrict__ k_o, float* __restrict__ v_o) {
    int bt = blockIdx.x; int b = bt / T; int t = bt % T;
    int tid = threadIdx.x;  // 128
    __shared__ __align__(16) float xs[D];
    int sid = session[bt];
    int es = t + 1 - (T - lengths[b]); if (es < 0) es = 0;
    float x = I_emb[(size_t)sid * D + tid] + ES_emb[es * D + tid];
    xs[tid] = x;
    __syncthreads();
    float aq = 0.f, ak = 0.f, av = 0.f;
    const float4* wq4 = (const float4*)(Wq + tid * D);
    const float4* wk4 = (const float4*)(Wk + tid * D);
    const float4* wv4 = (const float4*)(Wv + tid * D);
    const float4* x4  = (const float4*)xs;
    #pragma unroll 8
    for (int k = 0; k < D / 4; ++k) {
        float4 xv = x4[k];
        float4 a = wq4[k], bq = wk4[k], c = wv4[k];
        aq += xv.x * a.x + xv.y * a.y + xv.z * a.z + xv.w * a.w;
        ak += xv.x * bq.x + xv.y * bq.y + xv.z * bq.z + xv.w * bq.w;
        av += xv.x * c.x + xv.y * c.y + xv.z * c.z + xv.w * c.w;
    }
    xs_o[bt * D + tid] = x; q_o[bt * D + tid] = aq; k_o[bt * D + tid] = ak; v_o[bt * D + tid] = av;
}

// ---------------- 4. attention: scores + softmax + attn@vv ----------------
__global__ void k_attn(const int* __restrict__ session,
                       const float* __restrict__ q,
                       const float* __restrict__ kk,
                       const float* __restrict__ vv,
                       float* __restrict__ ho) {
    int bt = blockIdx.x; int b = bt / T; int t = bt % T;
    int tid = threadIdx.x;  // 128
    __shared__ __align__(16) float qs[D];
    __shared__ float attn[64];
    qs[tid] = q[bt * D + tid];
    __syncthreads();
    if (tid < T) {
        int s = tid;
        bool allowed = (s == 0) || ((s <= t) && (session[b * T + s] != 0));
        float sc = -1e9f;
        if (allowed) {
            float a = 0.f;
            const float4* kr = (const float4*)(kk + (size_t)(b * T + s) * D);
            const float4* q4 = (const float4*)qs;
            #pragma unroll 8
            for (int d = 0; d < D / 4; ++d) {
                float4 kv = kr[d]; float4 qv = q4[d];
                a += qv.x * kv.x + qv.y * kv.y + qv.z * kv.z + qv.w * kv.w;
            }
            sc = a * 0.088388347648318447f;  // 1/sqrt(128)
        }
        attn[s] = sc;
    }
    __syncthreads();
    if (tid < 64) {
        float vsc = (tid < T) ? attn[tid] : -1e30f;
        float m = vsc;
        for (int off = 32; off > 0; off >>= 1) m = fmaxf(m, __shfl_xor(m, off, 64));
        float e = (tid < T) ? expf(vsc - m) : 0.f;
        float ssum = e;
        for (int off = 32; off > 0; off >>= 1) ssum += __shfl_xor(ssum, off, 64);
        if (tid < T) attn[tid] = e / ssum;
    }
    __syncthreads();
    float acc = 0.f;
    for (int s = 0; s < T; ++s) acc += attn[s] * vv[(size_t)(b * T + s) * D + tid];
    ho[bt * D + tid] = acc;
}

// ---------------- 5. Wo + residual + LN1 ----------------
__global__ void k_post_attn(const int* __restrict__ session,
                            const float* __restrict__ ho,
                            const float* __restrict__ Wo,
                            const float* __restrict__ xs,
                            const float* __restrict__ g1, const float* __restrict__ b1,
                            float* __restrict__ h_o) {
    int bt = blockIdx.x; int tid = threadIdx.x;
    __shared__ __align__(16) float hr[D];
    __shared__ float sbuf[2];
    hr[tid] = ho[bt * D + tid];
    __syncthreads();
    float a = 0.f;
    const float4* w4 = (const float4*)(Wo + tid * D);
    const float4* h4 = (const float4*)hr;
    #pragma unroll 8
    for (int k = 0; k < D / 4; ++k) {
        float4 w = w4[k]; float4 hv = h4[k];
        a += hv.x * w.x + hv.y * w.y + hv.z * w.z + hv.w * w.w;
    }
    float x = a + xs[bt * D + tid];
    float mean = blockReduceSum128(x, sbuf) * (1.f / D);
    float dx = x - mean;
    float var = blockReduceSum128(dx * dx, sbuf) * (1.f / D);
    float y = dx * rsqrtf(var + 1e-6f) * g1[tid] + b1[tid];
    h_o[bt * D + tid] = y * ((session[bt] != 0) ? 1.f : 0.f);
}

// ---------------- 6. FFN + LN2 + projection -> G(bf16), Fn2 ----------------
__global__ void k_ffn_G(const int* __restrict__ session,
                        const float* __restrict__ h,
                        const float* __restrict__ FF1, const float* __restrict__ FF2,
                        const float* __restrict__ g2, const float* __restrict__ b2,
                        const float* __restrict__ ps, const float* __restrict__ v,
                        short* __restrict__ G16, float* __restrict__ Fn2) {
    int bt = blockIdx.x; int b = bt / T; int tid = threadIdx.x;
    __shared__ __align__(16) float hr[D];
    __shared__ __align__(16) float t1[D];
    __shared__ float sbuf[2];
    float hx = h[bt * D + tid];
    hr[tid] = hx;
    __syncthreads();
    float a = 0.f;
    const float4* w14 = (const float4*)(FF1 + tid * D);
    const float4* h4 = (const float4*)hr;
    #pragma unroll 8
    for (int k = 0; k < D / 4; ++k) {
        float4 w = w14[k]; float4 hv = h4[k];
        a += hv.x * w.x + hv.y * w.y + hv.z * w.z + hv.w * w.w;
    }
    t1[tid] = fmaxf(a, 0.f);
    __syncthreads();
    float f = 0.f;
    const float4* w24 = (const float4*)(FF2 + tid * D);
    const float4* t4 = (const float4*)t1;
    #pragma unroll 8
    for (int k = 0; k < D / 4; ++k) {
        float4 w = w24[k]; float4 tv = t4[k];
        f += tv.x * w.x + tv.y * w.y + tv.z * w.z + tv.w * w.w;
    }
    float x = f + hx;
    float mean = blockReduceSum128(x, sbuf) * (1.f / D);
    float dx = x - mean;
    float var = blockReduceSum128(dx * dx, sbuf) * (1.f / D);
    float ss = dx * rsqrtf(var + 1e-6f) * g2[tid] + b2[tid];
    ss *= (session[bt] != 0) ? 1.f : 0.f;
    float vb = v[b * D + tid];
    float vs = blockReduceSum128(vb * ss, sbuf);
    float ssp = ss - vb * vs;                  // s_s_proj
    float Fd = ps[b * D + tid] + ssp;          // F
    float Fv = blockReduceSum128(Fd * vb, sbuf);
    float Gd = Fd - Fv * vb;                   // G = F - (F.v) v
    float fn2 = blockReduceSum128(Fd * Fd, sbuf);
    G16[bt * D + tid] = (short)f2bf(Gd);
    if (tid == 0) Fn2[bt] = fn2;
}

// ---------------- 7. per-item stats: In2pb[b,n] = ||I_n||^2 - (v_b . I_n)^2 ----------------
__global__ void k_item(const float* __restrict__ I_emb,
                       const float* __restrict__ v,
                       float* __restrict__ In2pb) {
    __shared__ float Is[64][129];
    __shared__ float vs[B][D];
    __shared__ float in2[64];
    int n0 = blockIdx.x * 64;
    int tid = threadIdx.x;  // 256
    for (int i = tid; i < B * D; i += 256) vs[i / D][i % D] = v[i];
    for (int i = tid; i < 64 * D; i += 256) {
        int r = i / D, c = i % D;
        int n = n0 + r;
        Is[r][c] = (n < N1) ? I_emb[(size_t)n * D + c] : 0.f;
    }
    __syncthreads();
    if (tid < 64) {
        float s = 0.f;
        for (int d = 0; d < D; ++d) { float z = Is[tid][d]; s += z * z; }
        in2[tid] = s;
    }
    __syncthreads();
    int nl = tid & 63;
    int b0 = (tid >> 6) * 8;
    int n = n0 + nl;
    if (n < N1) {
        for (int b = b0; b < b0 + 8; ++b) {
            float dot = 0.f;
            for (int d = 0; d < D; ++d) dot += Is[nl][d] * vs[b][d];
            In2pb[(size_t)b * N1 + n] = in2[nl] - dot * dot;
        }
    }
}

// ---------------- 8. big dist kernel: bf16 MFMA, 64x64 tile, K=128 in one shot ----------------
// I is converted fp32->bf16 during staging (no separate I16 buffer; keeps ws small).
#define LDK 136   // 128 + 8 pad shorts -> 272B row stride, balanced bank groups on ds_read_b128
__global__ __launch_bounds__(256) void k_dist_mfma(const short* __restrict__ G16,
                                                   const float* __restrict__ I,
                                                   const float* __restrict__ Fn2,
                                                   const float* __restrict__ In2pb,
                                                   float* __restrict__ out) {
    __shared__ __align__(16) short As[64][LDK];
    __shared__ __align__(16) short Bs[64][LDK];
    int bt0 = blockIdx.y * 64;
    int n0  = blockIdx.x * 64;
    int tid = threadIdx.x;
    // A staging: 64 rows x 128 shorts, 16B per thread per row-slice
    int r = tid >> 4;          // 0..15
    int c = (tid & 15) * 8;    // short offset
    #pragma unroll
    for (int s = 0; s < 4; ++s) {
        int row = r + s * 16;
        *(short8v*)&As[row][c] = *(const short8v*)&G16[(size_t)(bt0 + row) * D + c];
    }
    // B staging: 64 rows x 128 floats -> bf16. thread: row=tid>>2, cols [(tid&3)*32, +32)
    {
        int br = tid >> 2;
        int bq = (tid & 3) * 32;
        int n = n0 + br;
        if (n < N1) {
            const float4* src = (const float4*)&I[(size_t)n * D + bq];
            #pragma unroll
            for (int s = 0; s < 8; ++s) {
                float4 f = src[s];
                ushort4 u;
                u.x = f2bf(f.x); u.y = f2bf(f.y); u.z = f2bf(f.z); u.w = f2bf(f.w);
                *(ushort4*)&Bs[br][bq + s * 4] = u;
            }
        } else {
            #pragma unroll
            for (int s = 0; s < 8; ++s)
                *(ushort4*)&Bs[br][bq + s * 4] = make_ushort4(0, 0, 0, 0);
        }
    }
    __syncthreads();
    int w  = tid >> 6;   // wave 0..3 -> A rows [w*16, w*16+16)
    int l  = tid & 63;
    int lr = l & 15;
    int lg = l >> 4;
    f32x4 acc[4] = {{0.f,0.f,0.f,0.f},{0.f,0.f,0.f,0.f},{0.f,0.f,0.f,0.f},{0.f,0.f,0.f,0.f}};
    short8v af[4];
    #pragma unroll
    for (int ks = 0; ks < 4; ++ks)
        af[ks] = *(const short8v*)&As[w * 16 + lr][ks * 32 + lg * 8];
    #pragma unroll
    for (int nt = 0; nt < 4; ++nt) {
        #pragma unroll
        for (int ks = 0; ks < 4; ++ks) {
            short8v bf = *(const short8v*)&Bs[nt * 16 + lr][ks * 32 + lg * 8];
            acc[nt] = __builtin_amdgcn_mfma_f32_16x16x32_bf16(af[ks], bf, acc[nt], 0, 0, 0);
        }
    }
    // epilogue: out = Fn2[row] + In2pb[b][col] - 2*dot
    #pragma unroll
    for (int nt = 0; nt < 4; ++nt) {
        int col = n0 + nt * 16 + lr;
        if (col < N1) {
            #pragma unroll
            for (int i = 0; i < 4; ++i) {
                int row = bt0 + w * 16 + lg * 4 + i;
                int b = row / T;
                out[(size_t)row * N1 + col] = Fn2[row] + In2pb[(size_t)b * N1 + col] - 2.f * acc[nt][i];
            }
        }
    }
}

// ---------------- launch ----------------
extern "C" void kernel_launch(void* const* d_in, const int* in_sizes, int n_in,
                              void* d_out, int out_size, void* d_ws, size_t ws_size,
                              hipStream_t stream) {
    const int*   session = (const int*)d_in[0];
    const int*   lengths = (const int*)d_in[1];
    const int*   tau     = (const int*)d_in[2];
    const float* I_emb   = (const float*)d_in[5];
    const float* P_emb   = (const float*)d_in[6];
    const float* EP      = (const float*)d_in[7];
    const float* ES      = (const float*)d_in[8];
    const float* V       = (const float*)d_in[9];
    const float* WP1     = (const float*)d_in[10];
    const float* WP2     = (const float*)d_in[11];
    const float* Wq      = (const float*)d_in[12];
    const float* Wk      = (const float*)d_in[13];
    const float* Wv      = (const float*)d_in[14];
    const float* Wo      = (const float*)d_in[15];
    const float* FF1     = (const float*)d_in[16];
    const float* FF2     = (const float*)d_in[17];
    const float* g1      = (const float*)d_in[18];
    const float* b1      = (const float*)d_in[19];
    const float* g2      = (const float*)d_in[20];
    const float* b2      = (const float*)d_in[21];
    float* out = (float*)d_out;
    float* ws  = (float*)d_ws;

    // workspace layout (floats) — total ~2,966,624 floats ≈ 11.9 MB
    float* wsX2   = ws;                       // 25600
    float* wsPs   = wsX2 + 25600;             // 4096
    float* wsV    = wsPs + 4096;              // 4096
    float* wsXs   = wsV + 4096;               // 204800 each, x6
    float* wsQ    = wsXs + 204800;
    float* wsK    = wsQ + 204800;
    float* wsVv   = wsK + 204800;
    float* wsHo   = wsVv + 204800;
    float* wsH    = wsHo + 204800;
    float* wsFn2  = wsH + 204800;             // 1600
    float* wsIn2  = wsFn2 + 1600;             // 32*50001 = 1600032
    short* wsG16  = (short*)(wsIn2 + 1600032);  // 204800 shorts = 102400 floats

    float* orth_out = out + (size_t)BT * N1;

    k_proxy_x2 <<<BT, 128, 0, stream>>>(session, I_emb, EP, WP1, WP2, wsX2);
    k_proxy_head<<<B, 128, 0, stream>>>(wsX2, lengths, tau, P_emb, V, wsPs, wsV, orth_out);
    k_xs_qkv  <<<BT, 128, 0, stream>>>(session, lengths, I_emb, ES, Wq, Wk, Wv,
                                       wsXs, wsQ, wsK, wsVv);
    k_attn    <<<BT, 128, 0, stream>>>(session, wsQ, wsK, wsVv, wsHo);
    k_post_attn<<<BT, 128, 0, stream>>>(session, wsHo, Wo, wsXs, g1, b1, wsH);
    k_ffn_G   <<<BT, 128, 0, stream>>>(session, wsH, FF1, FF2, g2, b2, wsPs, wsV,
                                       wsG16, wsFn2);
    k_item    <<<(N1 + 63) / 64, 256, 0, stream>>>(I_emb, wsV, wsIn2);
    dim3 gdist((N1 + 63) / 64, BT / 64);
    k_dist_mfma<<<gdist, 256, 0, stream>>>(wsG16, I_emb, wsFn2, wsIn2, out);
}

// Round 4
// 308.309 us; speedup vs baseline: 1.9182x; 1.4777x over previous
//
#include <hip/hip_runtime.h>
#include <math.h>

#define B   32
#define T   50
#define N1  50001
#define D   128
#define KP  16
#define MP  50
#define HID 72
#define BT  (B*T)

typedef __attribute__((ext_vector_type(8))) short short8v;
typedef __attribute__((ext_vector_type(4))) float f32x4;

__device__ __forceinline__ unsigned short f2bf(float x) {
    unsigned u = __float_as_uint(x);
    u += 0x7fffu + ((u >> 16) & 1u);
    return (unsigned short)(u >> 16);
}

// ---------------- helpers ----------------
__device__ __forceinline__ float blockReduceSum128(float val, volatile float* sbuf) {
    // blockDim.x == 128 (2 waves of 64)
    for (int off = 32; off > 0; off >>= 1) val += __shfl_down(val, off, 64);
    __syncthreads();                       // protect sbuf from previous use
    if ((threadIdx.x & 63) == 0) sbuf[threadIdx.x >> 6] = val;
    __syncthreads();
    return sbuf[0] + sbuf[1];
}

// ---------------- 1. ProxySelection MLP per (b,t) ----------------
__global__ void k_proxy_x2(const int* __restrict__ session,
                           const float* __restrict__ I_emb,
                           const float* __restrict__ EP_emb,
                           const float* __restrict__ WP1,
                           const float* __restrict__ WP2,
                           float* __restrict__ X2) {
    int bt = blockIdx.x; int t = bt % T;
    int tid = threadIdx.x;                 // 128
    __shared__ __align__(16) float x[D];
    __shared__ float h[HID];
    int sid = session[bt];
    float val = 0.f;
    if (sid != 0) val = I_emb[(size_t)sid * D + tid] + EP_emb[(t + MP - T) * D + tid];
    x[tid] = val;
    __syncthreads();
    if (tid < HID) {
        float acc = 0.f;
        const float4* w4 = (const float4*)(WP1 + tid * D);
        const float4* x4 = (const float4*)x;
        #pragma unroll 8
        for (int k = 0; k < D / 4; ++k) {
            float4 w = w4[k]; float4 xv = x4[k];
            acc += xv.x * w.x + xv.y * w.y + xv.z * w.z + xv.w * w.w;
        }
        h[tid] = acc > 0.f ? acc : 0.1f * acc;   // leaky_relu 0.1
    }
    __syncthreads();
    if (tid < KP) {
        float acc = 0.f;
        const float* w = WP2 + tid * HID;
        for (int k = 0; k < HID; ++k) acc += h[k] * w[k];
        X2[bt * KP + tid] = acc;
    }
}

// ---------------- 2. softmax head: pi, p_s, v, orthogonal ----------------
__global__ void k_proxy_head(const float* __restrict__ X2,
                             const int* __restrict__ lengths,
                             const int* __restrict__ tau_i,
                             const float* __restrict__ P_emb,
                             const float* __restrict__ V,
                             float* __restrict__ ps_o,
                             float* __restrict__ v_o,
                             float* __restrict__ orth_o) {
    int b = blockIdx.x; int tid = threadIdx.x;   // 128
    __shared__ float pi[KP];
    __shared__ float vn[KP];
    __shared__ float sbuf[2];
    float tau = (float)tau_i[0];
    float lf = (float)lengths[b];
    if (tid < KP) {
        float s = 0.f;
        for (int t = 0; t < T; ++t) s += X2[(b * T + t) * KP + tid];
        pi[tid] = (s / lf) / tau;
    }
    if (tid < KP) {   // V row norms
        float s = 0.f;
        for (int d = 0; d < D; ++d) { float z = V[tid * D + d]; s += z * z; }
        vn[tid] = fmaxf(sqrtf(s), 1e-12f);
    }
    __syncthreads();
    if (tid == 0) {
        float m = pi[0];
        for (int k = 1; k < KP; ++k) m = fmaxf(m, pi[k]);
        float s = 0.f;
        for (int k = 0; k < KP; ++k) { float e = expf(pi[k] - m); pi[k] = e; s += e; }
        for (int k = 0; k < KP; ++k) pi[k] /= s;
    }
    __syncthreads();
    float p = 0.f, vt = 0.f;
    for (int k = 0; k < KP; ++k) {
        p  += pi[k] * P_emb[k * D + tid];
        vt += pi[k] * (V[k * D + tid] / vn[k]);
    }
    float vsq = blockReduceSum128(vt * vt, sbuf);
    float vv = vt / fmaxf(sqrtf(vsq), 1e-12f);
    float psq = blockReduceSum128(p * p, sbuf);
    float dvp = blockReduceSum128(vv * p, sbuf);
    ps_o[b * D + tid] = p;
    v_o[b * D + tid] = vv;
    if (tid == 0) orth_o[b] = fabsf(dvp) / sqrtf(psq);
}

// ---------------- 3. Xs, q, k, v ----------------
__global__ void k_xs_qkv(const int* __restrict__ session,
                         const int* __restrict__ lengths,
                         const float* __restrict__ I_emb,
                         const float* __restrict__ ES_emb,
                         const float* __restrict__ Wq,
                         const float* __restrict__ Wk,
                         const float* __restrict__ Wv,
                         float* __restrict__ xs_o, float* __restrict__ q_o,
                         float* __restrict__ k_o, float* __restrict__ v_o) {
    int bt = blockIdx.x; int b = bt / T; int t = bt % T;
    int tid = threadIdx.x;  // 128
    __shared__ __align__(16) float xs[D];
    int sid = session[bt];
    int es = t + 1 - (T - lengths[b]); if (es < 0) es = 0;
    float x = I_emb[(size_t)sid * D + tid] + ES_emb[es * D + tid];
    xs[tid] = x;
    __syncthreads();
    float aq = 0.f, ak = 0.f, av = 0.f;
    const float4* wq4 = (const float4*)(Wq + tid * D);
    const float4* wk4 = (const float4*)(Wk + tid * D);
    const float4* wv4 = (const float4*)(Wv + tid * D);
    const float4* x4  = (const float4*)xs;
    #pragma unroll 8
    for (int k = 0; k < D / 4; ++k) {
        float4 xv = x4[k];
        float4 a = wq4[k], bq = wk4[k], c = wv4[k];
        aq += xv.x * a.x + xv.y * a.y + xv.z * a.z + xv.w * a.w;
        ak += xv.x * bq.x + xv.y * bq.y + xv.z * bq.z + xv.w * bq.w;
        av += xv.x * c.x + xv.y * c.y + xv.z * c.z + xv.w * c.w;
    }
    xs_o[bt * D + tid] = x; q_o[bt * D + tid] = aq; k_o[bt * D + tid] = ak; v_o[bt * D + tid] = av;
}

// ---------------- 4. attention: scores + softmax + attn@vv ----------------
__global__ void k_attn(const int* __restrict__ session,
                       const float* __restrict__ q,
                       const float* __restrict__ kk,
                       const float* __restrict__ vv,
                       float* __restrict__ ho) {
    int bt = blockIdx.x; int b = bt / T; int t = bt % T;
    int tid = threadIdx.x;  // 128
    __shared__ __align__(16) float qs[D];
    __shared__ float attn[64];
    qs[tid] = q[bt * D + tid];
    __syncthreads();
    if (tid < T) {
        int s = tid;
        bool allowed = (s == 0) || ((s <= t) && (session[b * T + s] != 0));
        float sc = -1e9f;
        if (allowed) {
            float a = 0.f;
            const float4* kr = (const float4*)(kk + (size_t)(b * T + s) * D);
            const float4* q4 = (const float4*)qs;
            #pragma unroll 8
            for (int d = 0; d < D / 4; ++d) {
                float4 kv = kr[d]; float4 qv = q4[d];
                a += qv.x * kv.x + qv.y * kv.y + qv.z * kv.z + qv.w * kv.w;
            }
            sc = a * 0.088388347648318447f;  // 1/sqrt(128)
        }
        attn[s] = sc;
    }
    __syncthreads();
    if (tid < 64) {
        float vsc = (tid < T) ? attn[tid] : -1e30f;
        float m = vsc;
        for (int off = 32; off > 0; off >>= 1) m = fmaxf(m, __shfl_xor(m, off, 64));
        float e = (tid < T) ? expf(vsc - m) : 0.f;
        float ssum = e;
        for (int off = 32; off > 0; off >>= 1) ssum += __shfl_xor(ssum, off, 64);
        if (tid < T) attn[tid] = e / ssum;
    }
    __syncthreads();
    float acc = 0.f;
    for (int s = 0; s < T; ++s) acc += attn[s] * vv[(size_t)(b * T + s) * D + tid];
    ho[bt * D + tid] = acc;
}

// ---------------- 5. Wo + residual + LN1 ----------------
__global__ void k_post_attn(const int* __restrict__ session,
                            const float* __restrict__ ho,
                            const float* __restrict__ Wo,
                            const float* __restrict__ xs,
                            const float* __restrict__ g1, const float* __restrict__ b1,
                            float* __restrict__ h_o) {
    int bt = blockIdx.x; int tid = threadIdx.x;
    __shared__ __align__(16) float hr[D];
    __shared__ float sbuf[2];
    hr[tid] = ho[bt * D + tid];
    __syncthreads();
    float a = 0.f;
    const float4* w4 = (const float4*)(Wo + tid * D);
    const float4* h4 = (const float4*)hr;
    #pragma unroll 8
    for (int k = 0; k < D / 4; ++k) {
        float4 w = w4[k]; float4 hv = h4[k];
        a += hv.x * w.x + hv.y * w.y + hv.z * w.z + hv.w * w.w;
    }
    float x = a + xs[bt * D + tid];
    float mean = blockReduceSum128(x, sbuf) * (1.f / D);
    float dx = x - mean;
    float var = blockReduceSum128(dx * dx, sbuf) * (1.f / D);
    float y = dx * rsqrtf(var + 1e-6f) * g1[tid] + b1[tid];
    h_o[bt * D + tid] = y * ((session[bt] != 0) ? 1.f : 0.f);
}

// ---------------- 6. FFN + LN2 + projection -> G(bf16), Fn2 ----------------
__global__ void k_ffn_G(const int* __restrict__ session,
                        const float* __restrict__ h,
                        const float* __restrict__ FF1, const float* __restrict__ FF2,
                        const float* __restrict__ g2, const float* __restrict__ b2,
                        const float* __restrict__ ps, const float* __restrict__ v,
                        short* __restrict__ G16, float* __restrict__ Fn2) {
    int bt = blockIdx.x; int b = bt / T; int tid = threadIdx.x;
    __shared__ __align__(16) float hr[D];
    __shared__ __align__(16) float t1[D];
    __shared__ float sbuf[2];
    float hx = h[bt * D + tid];
    hr[tid] = hx;
    __syncthreads();
    float a = 0.f;
    const float4* w14 = (const float4*)(FF1 + tid * D);
    const float4* h4 = (const float4*)hr;
    #pragma unroll 8
    for (int k = 0; k < D / 4; ++k) {
        float4 w = w14[k]; float4 hv = h4[k];
        a += hv.x * w.x + hv.y * w.y + hv.z * w.z + hv.w * w.w;
    }
    t1[tid] = fmaxf(a, 0.f);
    __syncthreads();
    float f = 0.f;
    const float4* w24 = (const float4*)(FF2 + tid * D);
    const float4* t4 = (const float4*)t1;
    #pragma unroll 8
    for (int k = 0; k < D / 4; ++k) {
        float4 w = w24[k]; float4 tv = t4[k];
        f += tv.x * w.x + tv.y * w.y + tv.z * w.z + tv.w * w.w;
    }
    float x = f + hx;
    float mean = blockReduceSum128(x, sbuf) * (1.f / D);
    float dx = x - mean;
    float var = blockReduceSum128(dx * dx, sbuf) * (1.f / D);
    float ss = dx * rsqrtf(var + 1e-6f) * g2[tid] + b2[tid];
    ss *= (session[bt] != 0) ? 1.f : 0.f;
    float vb = v[b * D + tid];
    float vs = blockReduceSum128(vb * ss, sbuf);
    float ssp = ss - vb * vs;                  // s_s_proj
    float Fd = ps[b * D + tid] + ssp;          // F
    float Fv = blockReduceSum128(Fd * vb, sbuf);
    float Gd = Fd - Fv * vb;                   // G = F - (F.v) v
    float fn2 = blockReduceSum128(Fd * Fd, sbuf);
    G16[bt * D + tid] = (short)f2bf(Gd);
    if (tid == 0) Fn2[bt] = fn2;
}

#define LDK 136   // 128 + 8 pad shorts -> 272B row stride, balanced bank groups on ds_read_b128

// ---------------- 7. per-item stats via MFMA: In2pb[b,n] = ||I_n||^2 - (v_b . I_n)^2 ----------------
// vI = I[64-tile,128] x v^T[128,32] on matrix cores; In2 accumulated fp32 during staging.
__global__ __launch_bounds__(256) void k_item_mfma(const float* __restrict__ I,
                                                   const float* __restrict__ v,
                                                   float* __restrict__ In2pb) {
    __shared__ __align__(16) short Is[64][LDK];
    __shared__ __align__(16) short Vs[32][LDK];
    __shared__ float sq[64][4];
    __shared__ float in2[64];
    int n0 = blockIdx.x * 64;
    int tid = threadIdx.x;   // 256
    // stage v: 32 rows x 128 fp32 -> bf16; thread: row=tid>>3, cols [(tid&7)*16, +16)
    {
        int vr = tid >> 3;
        int vc = (tid & 7) * 16;
        const float4* src = (const float4*)&v[vr * D + vc];
        #pragma unroll
        for (int s = 0; s < 4; ++s) {
            float4 f = src[s];
            ushort4 u;
            u.x = f2bf(f.x); u.y = f2bf(f.y); u.z = f2bf(f.z); u.w = f2bf(f.w);
            *(ushort4*)&Vs[vr][vc + s * 4] = u;
        }
    }
    // stage I rows: row=tid>>2, cols [(tid&3)*32, +32); fp32 sqsum partials
    {
        int r = tid >> 2;
        int q = tid & 3;
        int n = n0 + r;
        float ss = 0.f;
        if (n < N1) {
            const float4* src = (const float4*)&I[(size_t)n * D + q * 32];
            #pragma unroll
            for (int s = 0; s < 8; ++s) {
                float4 f = src[s];
                ss += f.x * f.x + f.y * f.y + f.z * f.z + f.w * f.w;
                ushort4 u;
                u.x = f2bf(f.x); u.y = f2bf(f.y); u.z = f2bf(f.z); u.w = f2bf(f.w);
                *(ushort4*)&Is[r][q * 32 + s * 4] = u;
            }
        } else {
            #pragma unroll
            for (int s = 0; s < 8; ++s)
                *(ushort4*)&Is[r][q * 32 + s * 4] = make_ushort4(0, 0, 0, 0);
        }
        sq[r][q] = ss;
    }
    __syncthreads();
    if (tid < 64) in2[tid] = sq[tid][0] + sq[tid][1] + sq[tid][2] + sq[tid][3];
    __syncthreads();
    // MFMA: wave w owns items [w*16, w*16+16); B = v rows (2 tiles of 16)
    int w = tid >> 6, l = tid & 63, lr = l & 15, lg = l >> 4;
    f32x4 acc[2] = {{0.f,0.f,0.f,0.f},{0.f,0.f,0.f,0.f}};
    short8v af[4];
    #pragma unroll
    for (int ks = 0; ks < 4; ++ks)
        af[ks] = *(const short8v*)&Is[w * 16 + lr][ks * 32 + lg * 8];
    #pragma unroll
    for (int nt = 0; nt < 2; ++nt) {
        #pragma unroll
        for (int ks = 0; ks < 4; ++ks) {
            short8v bf = *(const short8v*)&Vs[nt * 16 + lr][ks * 32 + lg * 8];
            acc[nt] = __builtin_amdgcn_mfma_f32_16x16x32_bf16(af[ks], bf, acc[nt], 0, 0, 0);
        }
    }
    // C layout: b = nt*16 + lr (col), item = w*16 + lg*4 + i (row)
    #pragma unroll
    for (int nt = 0; nt < 2; ++nt) {
        int b = nt * 16 + lr;
        #pragma unroll
        for (int i = 0; i < 4; ++i) {
            int item = w * 16 + lg * 4 + i;
            int n = n0 + item;
            if (n < N1) {
                float dvi = acc[nt][i];
                In2pb[(size_t)b * N1 + n] = in2[item] - dvi * dvi;
            }
        }
    }
}

// ---------------- 8. big dist kernel: bf16 MFMA, 64x64 tile, K=128 in one shot ----------------
// I is converted fp32->bf16 during staging (no separate I16 buffer; keeps ws small).
__global__ __launch_bounds__(256) void k_dist_mfma(const short* __restrict__ G16,
                                                   const float* __restrict__ I,
                                                   const float* __restrict__ Fn2,
                                                   const float* __restrict__ In2pb,
                                                   float* __restrict__ out) {
    __shared__ __align__(16) short As[64][LDK];
    __shared__ __align__(16) short Bs[64][LDK];
    int bt0 = blockIdx.y * 64;
    int n0  = blockIdx.x * 64;
    int tid = threadIdx.x;
    // A staging: 64 rows x 128 shorts, 16B per thread per row-slice
    int r = tid >> 4;          // 0..15
    int c = (tid & 15) * 8;    // short offset
    #pragma unroll
    for (int s = 0; s < 4; ++s) {
        int row = r + s * 16;
        *(short8v*)&As[row][c] = *(const short8v*)&G16[(size_t)(bt0 + row) * D + c];
    }
    // B staging: 64 rows x 128 floats -> bf16. thread: row=tid>>2, cols [(tid&3)*32, +32)
    {
        int br = tid >> 2;
        int bq = (tid & 3) * 32;
        int n = n0 + br;
        if (n < N1) {
            const float4* src = (const float4*)&I[(size_t)n * D + bq];
            #pragma unroll
            for (int s = 0; s < 8; ++s) {
                float4 f = src[s];
                ushort4 u;
                u.x = f2bf(f.x); u.y = f2bf(f.y); u.z = f2bf(f.z); u.w = f2bf(f.w);
                *(ushort4*)&Bs[br][bq + s * 4] = u;
            }
        } else {
            #pragma unroll
            for (int s = 0; s < 8; ++s)
                *(ushort4*)&Bs[br][bq + s * 4] = make_ushort4(0, 0, 0, 0);
        }
    }
    __syncthreads();
    int w  = tid >> 6;   // wave 0..3 -> A rows [w*16, w*16+16)
    int l  = tid & 63;
    int lr = l & 15;
    int lg = l >> 4;
    f32x4 acc[4] = {{0.f,0.f,0.f,0.f},{0.f,0.f,0.f,0.f},{0.f,0.f,0.f,0.f},{0.f,0.f,0.f,0.f}};
    short8v af[4];
    #pragma unroll
    for (int ks = 0; ks < 4; ++ks)
        af[ks] = *(const short8v*)&As[w * 16 + lr][ks * 32 + lg * 8];
    #pragma unroll
    for (int nt = 0; nt < 4; ++nt) {
        #pragma unroll
        for (int ks = 0; ks < 4; ++ks) {
            short8v bf = *(const short8v*)&Bs[nt * 16 + lr][ks * 32 + lg * 8];
            acc[nt] = __builtin_amdgcn_mfma_f32_16x16x32_bf16(af[ks], bf, acc[nt], 0, 0, 0);
        }
    }
    // epilogue: out = Fn2[row] + In2pb[b][col] - 2*dot
    #pragma unroll
    for (int nt = 0; nt < 4; ++nt) {
        int col = n0 + nt * 16 + lr;
        if (col < N1) {
            #pragma unroll
            for (int i = 0; i < 4; ++i) {
                int row = bt0 + w * 16 + lg * 4 + i;
                int b = row / T;
                out[(size_t)row * N1 + col] = Fn2[row] + In2pb[(size_t)b * N1 + col] - 2.f * acc[nt][i];
            }
        }
    }
}

// ---------------- launch ----------------
extern "C" void kernel_launch(void* const* d_in, const int* in_sizes, int n_in,
                              void* d_out, int out_size, void* d_ws, size_t ws_size,
                              hipStream_t stream) {
    const int*   session = (const int*)d_in[0];
    const int*   lengths = (const int*)d_in[1];
    const int*   tau     = (const int*)d_in[2];
    const float* I_emb   = (const float*)d_in[5];
    const float* P_emb   = (const float*)d_in[6];
    const float* EP      = (const float*)d_in[7];
    const float* ES      = (const float*)d_in[8];
    const float* V       = (const float*)d_in[9];
    const float* WP1     = (const float*)d_in[10];
    const float* WP2     = (const float*)d_in[11];
    const float* Wq      = (const float*)d_in[12];
    const float* Wk      = (const float*)d_in[13];
    const float* Wv      = (const float*)d_in[14];
    const float* Wo      = (const float*)d_in[15];
    const float* FF1     = (const float*)d_in[16];
    const float* FF2     = (const float*)d_in[17];
    const float* g1      = (const float*)d_in[18];
    const float* b1      = (const float*)d_in[19];
    const float* g2      = (const float*)d_in[20];
    const float* b2      = (const float*)d_in[21];
    float* out = (float*)d_out;
    float* ws  = (float*)d_ws;

    // workspace layout (floats) — total ~2,966,624 floats ≈ 11.9 MB
    float* wsX2   = ws;                       // 25600
    float* wsPs   = wsX2 + 25600;             // 4096
    float* wsV    = wsPs + 4096;              // 4096
    float* wsXs   = wsV + 4096;               // 204800 each, x6
    float* wsQ    = wsXs + 204800;
    float* wsK    = wsQ + 204800;
    float* wsVv   = wsK + 204800;
    float* wsHo   = wsVv + 204800;
    float* wsH    = wsHo + 204800;
    float* wsFn2  = wsH + 204800;             // 1600
    float* wsIn2  = wsFn2 + 1600;             // 32*50001 = 1600032
    short* wsG16  = (short*)(wsIn2 + 1600032);  // 204800 shorts = 102400 floats

    float* orth_out = out + (size_t)BT * N1;

    k_proxy_x2 <<<BT, 128, 0, stream>>>(session, I_emb, EP, WP1, WP2, wsX2);
    k_proxy_head<<<B, 128, 0, stream>>>(wsX2, lengths, tau, P_emb, V, wsPs, wsV, orth_out);
    k_xs_qkv  <<<BT, 128, 0, stream>>>(session, lengths, I_emb, ES, Wq, Wk, Wv,
                                       wsXs, wsQ, wsK, wsVv);
    k_attn    <<<BT, 128, 0, stream>>>(session, wsQ, wsK, wsVv, wsHo);
    k_post_attn<<<BT, 128, 0, stream>>>(session, wsHo, Wo, wsXs, g1, b1, wsH);
    k_ffn_G   <<<BT, 128, 0, stream>>>(session, wsH, FF1, FF2, g2, b2, wsPs, wsV,
                                       wsG16, wsFn2);
    k_item_mfma<<<(N1 + 63) / 64, 256, 0, stream>>>(I_emb, wsV, wsIn2);
    dim3 gdist((N1 + 63) / 64, BT / 64);
    k_dist_mfma<<<gdist, 256, 0, stream>>>(wsG16, I_emb, wsFn2, wsIn2, out);
}